// Round 1
// 566.461 us; speedup vs baseline: 1.0412x; 1.0412x over previous
//
#include <hip/hip_runtime.h>
#include <hip/hip_bf16.h>
#include <cstdint>

// Problem constants
// B=128, P=168, M=8, HIDC=50, HIDR=50, HIDS=5, CK=6, SKIP=24, HW=24
// O = P*HIDC*CK = 50400, Kdim = P*M = 1344, L = 163, PT = 6

typedef __attribute__((ext_vector_type(8))) short short8;   // 8 bf16 (4 VGPRs)
typedef __attribute__((ext_vector_type(4))) float f32x4;    // MFMA acc

__device__ __forceinline__ unsigned short bf16rn(float f) {
    unsigned u = __float_as_uint(f);
    return (unsigned short)((u + 0x7FFFu + ((u >> 16) & 1u)) >> 16);
}
__device__ __forceinline__ unsigned pk2(float a, float b) {
    return ((unsigned)bf16rn(b) << 16) | (unsigned)bf16rn(a);
}
__device__ __forceinline__ uint4 pack8(float4 f0, float4 f1) {
    uint4 u;
    u.x = pk2(f0.x, f0.y); u.y = pk2(f0.z, f0.w);
    u.z = pk2(f1.x, f1.y); u.w = pk2(f1.z, f1.w);
    return u;
}
__device__ __forceinline__ float bf2f(unsigned short u) {
    return __uint_as_float((unsigned)u << 16);
}
__device__ __forceinline__ float sigmf(float x) { return 1.f / (1.f + __expf(-x)); }
__device__ __forceinline__ float tanhf_(float x) { return 1.f - 2.f / (__expf(2.f * x) + 1.f); }

// ---------------------------------------------------------------------------
// K1: c[b][o] = relu(xf @ wf^T + conv_b), stored bf16.  M=128, N=50400, K=1344.
// (unchanged from previous verified version)
// ---------------------------------------------------------------------------
__global__ __launch_bounds__(256, 2)
void k1_conv_gemm(const float* __restrict__ x, const float* __restrict__ w,
                  const float* __restrict__ bias, unsigned short* __restrict__ c) {
    __shared__ uint4 a_lds[8 * 129];  // A: 128 rows (b), pad->129
    __shared__ uint4 b_lds[8 * 113];  // B: 112 rows (o), pad->113
    const int tid  = threadIdx.x;
    const int n0   = blockIdx.x * 112;
    const int wave = tid >> 6, lane = tid & 63;
    const int quad = lane >> 4, m16 = lane & 15;

    f32x4 acc[2][7];
#pragma unroll
    for (int i = 0; i < 2; ++i)
#pragma unroll
        for (int j = 0; j < 7; ++j) acc[i][j] = (f32x4){0.f, 0.f, 0.f, 0.f};

    float4 pa[4][2];  // A prefetch regs
    float4 pb[4][2];  // B prefetch regs

    auto issue = [&](int kb) {
#pragma unroll
        for (int i = 0; i < 4; ++i) {
            int row = (tid >> 3) + 32 * i;
            const float* gp = x + row * 1344 + kb + (tid & 7) * 8;
            pa[i][0] = *reinterpret_cast<const float4*>(gp);
            pa[i][1] = *reinterpret_cast<const float4*>(gp + 4);
        }
#pragma unroll
        for (int i = 0; i < 4; ++i) {
            int idx = tid + 256 * i;
            if (idx < 896) {
                int row = idx >> 3;
                const float* gp = w + (size_t)(n0 + row) * 1344 + kb + (idx & 7) * 8;
                pb[i][0] = *reinterpret_cast<const float4*>(gp);
                pb[i][1] = *reinterpret_cast<const float4*>(gp + 4);
            }
        }
    };

    issue(0);
    for (int kb = 0; kb < 1344; kb += 64) {
#pragma unroll
        for (int i = 0; i < 4; ++i) {
            int idx = tid + 256 * i;
            int row = idx >> 3, ks = idx & 7;
            a_lds[ks * 129 + row] = pack8(pa[i][0], pa[i][1]);
        }
#pragma unroll
        for (int i = 0; i < 4; ++i) {
            int idx = tid + 256 * i;
            if (idx < 896) {
                int row = idx >> 3, ks = idx & 7;
                b_lds[ks * 113 + row] = pack8(pb[i][0], pb[i][1]);
            }
        }
        __syncthreads();
        if (kb + 64 < 1344) issue(kb + 64);
#pragma unroll
        for (int half = 0; half < 2; ++half) {
            const int kp = half * 4 + quad;
            short8 af[2], bfr[7];
#pragma unroll
            for (int rt = 0; rt < 2; ++rt)
                af[rt] = ((const short8*)a_lds)[kp * 129 + wave * 32 + rt * 16 + m16];
#pragma unroll
            for (int ct = 0; ct < 7; ++ct)
                bfr[ct] = ((const short8*)b_lds)[kp * 113 + ct * 16 + m16];
#pragma unroll
            for (int rt = 0; rt < 2; ++rt)
#pragma unroll
                for (int ct = 0; ct < 7; ++ct)
                    acc[rt][ct] = __builtin_amdgcn_mfma_f32_16x16x32_bf16(
                        af[rt], bfr[ct], acc[rt][ct], 0, 0, 0);
        }
        __syncthreads();
    }
#pragma unroll
    for (int ct = 0; ct < 7; ++ct) {
        int col = n0 + ct * 16 + m16;
        float bv = bias[col];
#pragma unroll
        for (int rt = 0; rt < 2; ++rt) {
#pragma unroll
            for (int r = 0; r < 4; ++r) {
                int grow = wave * 32 + rt * 16 + quad * 4 + r;
                float v = acc[rt][ct][r] + bv;
                v = fmaxf(v, 0.f);
                c[(size_t)grow * 50400 + col] = bf16rn(v);
            }
        }
    }
}

// ---------------------------------------------------------------------------
// K_FUSED: everything after K1, one block per batch element b (128 blocks).
//   Phase A: rloc[hc][t] = sum_k c[b][hc*1008+169k+t]  (k2 logic, in LDS)
//   Phase B: gi1[t][150] and gi2[(pt*24+sk)][15] input projections, in LDS.
//            w rows are wave-uniform -> s_load broadcast.
//   Phase C: wave0 runs GRU1 (163 steps, h via LDS double-buffer, gi from
//            LDS); wave1 runs GRU2's 6 steps during the first 6 iterations.
//            One __syncthreads per step (all 6 waves).
//   Phase D: lanes 0..7 compute the final linear + highway + sigmoid.
// No intermediate global traffic (res1/gi1/gi2/r1/hs eliminated).
// ---------------------------------------------------------------------------
__global__ __launch_bounds__(384, 1)
void k_fused(const unsigned short* __restrict__ c,
             const float* __restrict__ g1_wih, const float* __restrict__ g1_whh,
             const float* __restrict__ g1_bih, const float* __restrict__ g1_bhh,
             const float* __restrict__ gs_wih, const float* __restrict__ gs_whh,
             const float* __restrict__ gs_bih, const float* __restrict__ gs_bhh,
             const float* __restrict__ l1_w, const float* __restrict__ l1_b,
             const float* __restrict__ x, const float* __restrict__ hw_w,
             const float* __restrict__ hw_b, float* __restrict__ out) {
    __shared__ float rloc[50 * 164];   // [hc][t] pad 163->164; reused as wl1[7500] in phase C
    __shared__ float gi1l[163 * 150];  // [t][150]
    __shared__ float gi2l[144 * 15];   // [(pt*24+sk)][15]
    __shared__ float l1wl[8 * 170];
    __shared__ __align__(16) float hl[2][64];
    __shared__ float hsl[120];
    __shared__ float r1l[64];

    const int b    = blockIdx.x;
    const int tid  = threadIdx.x;
    const int wave = tid >> 6, lane = tid & 63;

    // ---- Phase A: diagonal-sum into rloc (identical math to old k2) ----
    const unsigned short* cb = c + (size_t)b * 50400;
    for (int idx = tid; idx < 8150; idx += 384) {
        int hc = idx / 163, t = idx - hc * 163;
        int base = hc * 1008 + t;
        float s = 0.f;
#pragma unroll
        for (int k = 0; k < 6; ++k) s += bf2f(cb[base + 169 * k]);
        rloc[hc * 164 + t] = s;
    }
    for (int idx = tid; idx < 1360; idx += 384) l1wl[idx] = l1_w[idx];
    __syncthreads();

    // ---- Phase B: input projections gi1 / gi2 into LDS ----
    {
        // wave pairs own 64 consecutive t; half = wave&1 is wave-uniform so
        // weight-row addresses are uniform -> scalar loads.
        const int tB   = (wave >> 1) * 64 + lane;   // 0..191
        const int half = wave & 1;
        if (tB < 163) {
            float xcol[50];
#pragma unroll
            for (int j = 0; j < 50; ++j) xcol[j] = rloc[j * 164 + tB];

            const int c0 = __builtin_amdgcn_readfirstlane(half * 75);
            const float* wbase = g1_wih + c0 * 50;
            float* gdst = &gi1l[tB * 150 + c0];
            for (int cc = 0; cc < 75; ++cc) {
                const float* wp = wbase + cc * 50;
                float acc = g1_bih[c0 + cc];
#pragma unroll
                for (int j = 0; j < 50; ++j) acc += xcol[j] * wp[j];
                gdst[cc] = acc;
            }
            if (tB >= 19) {
                const int r2 = tB - 19;  // == pt*24 + sk (t = 19 + pt*24 + sk)
                const int d0 = __builtin_amdgcn_readfirstlane(half * 8);
                const int ncol = half ? 7 : 8;
                float* g2 = &gi2l[r2 * 15];
                for (int cc = 0; cc < ncol; ++cc) {
                    const float* wp = gs_wih + (d0 + cc) * 50;
                    float acc = gs_bih[d0 + cc];
#pragma unroll
                    for (int j = 0; j < 50; ++j) acc += xcol[j] * wp[j];
                    g2[d0 + cc] = acc;
                }
            }
        }
    }
    __syncthreads();

    // ---- Phase C setup: wave0 stages whh1 into rloc's space (rloc is dead),
    //      single-wave write->read needs no barrier (in-order LDS + lgkmcnt).
    float wr[50], wz[50], wn[50];
    float bhr = 0.f, bhz = 0.f, bhn = 0.f, hcur = 0.f;
    int lc = 0;
    float* wl1 = rloc;
    if (wave == 0) {
        for (int idx = lane; idx < 7500; idx += 64) wl1[idx] = g1_whh[idx];
        hl[0][lane] = 0.f;
        hl[1][lane] = 0.f;
        lc = (lane < 50) ? lane : 49;
#pragma unroll
        for (int j = 0; j < 50; ++j) {
            wr[j] = wl1[lc * 50 + j];
            wz[j] = wl1[(50 + lc) * 50 + j];
            wn[j] = wl1[(100 + lc) * 50 + j];
        }
        bhr = g1_bhh[lc]; bhz = g1_bhh[50 + lc]; bhn = g1_bhh[100 + lc];
    }
    float h2[5] = {0.f, 0.f, 0.f, 0.f, 0.f};  // GRU2 state (wave1 lanes<24)

    int p = 0;
    for (int t = 0; t < 163; ++t) {
        if (wave == 0) {
            float gir = gi1l[t * 150 + lc];
            float giz = gi1l[t * 150 + 50 + lc];
            float gin = gi1l[t * 150 + 100 + lc];
            const float* hp = hl[p];
            float ar = bhr, az = bhz, an = bhn;
#pragma unroll
            for (int j4 = 0; j4 < 12; ++j4) {
                float4 hv = *reinterpret_cast<const float4*>(hp + 4 * j4);
                ar += wr[4 * j4 + 0] * hv.x + wr[4 * j4 + 1] * hv.y +
                      wr[4 * j4 + 2] * hv.z + wr[4 * j4 + 3] * hv.w;
                az += wz[4 * j4 + 0] * hv.x + wz[4 * j4 + 1] * hv.y +
                      wz[4 * j4 + 2] * hv.z + wz[4 * j4 + 3] * hv.w;
                an += wn[4 * j4 + 0] * hv.x + wn[4 * j4 + 1] * hv.y +
                      wn[4 * j4 + 2] * hv.z + wn[4 * j4 + 3] * hv.w;
            }
            {
                float h48 = hp[48], h49 = hp[49];
                ar += wr[48] * h48 + wr[49] * h49;
                az += wz[48] * h48 + wz[49] * h49;
                an += wn[48] * h48 + wn[49] * h49;
            }
            float rg = sigmf(gir + ar);
            float zg = sigmf(giz + az);
            float ng = tanhf_(gin + rg * an);
            float hn = (1.f - zg) * ng + zg * hcur;
            hl[1 - p][lane] = hn;
            hcur = hn;
        } else if (wave == 1 && t < 6 && lane < 24) {
            // GRU2 step pt = t for sequence (b, sk=lane): overlaps GRU1
            const float* gp = &gi2l[(t * 24 + lane) * 15];
            float gi[15];
#pragma unroll
            for (int i = 0; i < 15; ++i) gi[i] = gp[i];
            float gh[15];
#pragma unroll
            for (int i = 0; i < 15; ++i) {
                float s = gs_bhh[i];
#pragma unroll
                for (int j = 0; j < 5; ++j) s += gs_whh[i * 5 + j] * h2[j];
                gh[i] = s;
            }
#pragma unroll
            for (int u = 0; u < 5; ++u) {
                float rg = sigmf(gi[u] + gh[u]);
                float zg = sigmf(gi[5 + u] + gh[5 + u]);
                float ng = tanhf_(gi[10 + u] + rg * gh[10 + u]);
                h2[u] = (1.f - zg) * ng + zg * h2[u];
            }
        }
        __syncthreads();
        p ^= 1;
    }
    if (wave == 0 && lane < 50) r1l[lane] = hcur;
    if (wave == 1 && lane < 24) {
#pragma unroll
        for (int u = 0; u < 5; ++u) hsl[lane * 5 + u] = h2[u];
    }
    __syncthreads();

    // ---- Phase D: final linear + highway + sigmoid, lanes 0..7 ----
    if (tid < 8) {
        const int m = tid;
        float acc = l1_b[m];
        const float* wrow = &l1wl[m * 170];
#pragma unroll
        for (int j = 0; j < 50; ++j) acc += r1l[j] * wrow[j];
#pragma unroll
        for (int j = 0; j < 120; ++j) acc += hsl[j] * wrow[50 + j];
        float z = hw_b[0];
        const float* xb = x + (size_t)b * 1344 + 144 * 8 + m;
#pragma unroll
        for (int wi = 0; wi < 24; ++wi) z += xb[wi * 8] * hw_w[wi];
        out[b * 8 + m] = 1.f / (1.f + __expf(-(acc + z)));
    }
}

// ---------------------------------------------------------------------------
extern "C" void kernel_launch(void* const* d_in, const int* in_sizes, int n_in,
                              void* d_out, int out_size, void* d_ws, size_t ws_size,
                              hipStream_t stream) {
    const float* x      = (const float*)d_in[0];
    const float* conv_w = (const float*)d_in[1];
    const float* conv_b = (const float*)d_in[2];
    const float* g1_wih = (const float*)d_in[3];
    const float* g1_whh = (const float*)d_in[4];
    const float* g1_bih = (const float*)d_in[5];
    const float* g1_bhh = (const float*)d_in[6];
    const float* gs_wih = (const float*)d_in[7];
    const float* gs_whh = (const float*)d_in[8];
    const float* gs_bih = (const float*)d_in[9];
    const float* gs_bhh = (const float*)d_in[10];
    const float* l1_w   = (const float*)d_in[11];
    const float* l1_b   = (const float*)d_in[12];
    const float* hw_w   = (const float*)d_in[13];
    const float* hw_b   = (const float*)d_in[14];
    float* out = (float*)d_out;

    // ws layout: only c now (12,902,400 B)
    unsigned short* c = (unsigned short*)d_ws;

    hipLaunchKernelGGL(k1_conv_gemm, dim3(450), dim3(256), 0, stream, x, conv_w, conv_b, c);
    hipLaunchKernelGGL(k_fused,      dim3(128), dim3(384), 0, stream,
                       c, g1_wih, g1_whh, g1_bih, g1_bhh,
                       gs_wih, gs_whh, gs_bih, gs_bhh,
                       l1_w, l1_b, x, hw_w, hw_b, out);
}

// Round 2
// 510.524 us; speedup vs baseline: 1.1553x; 1.1096x over previous
//
#include <hip/hip_runtime.h>
#include <hip/hip_bf16.h>
#include <cstdint>

// Problem constants
// B=128, P=168, M=8, HIDC=50, HIDR=50, HIDS=5, CK=6, SKIP=24, HW=24
// O = P*HIDC*CK = 50400, Kdim = P*M = 1344, L = 163, PT = 6

typedef __attribute__((ext_vector_type(8))) short short8;   // 8 bf16 (4 VGPRs)
typedef __attribute__((ext_vector_type(4))) float f32x4;    // MFMA acc
typedef __attribute__((ext_vector_type(2))) float f32x2;    // packed fp32 (v_pk_fma_f32)

__device__ __forceinline__ unsigned short bf16rn(float f) {
    unsigned u = __float_as_uint(f);
    return (unsigned short)((u + 0x7FFFu + ((u >> 16) & 1u)) >> 16);
}
__device__ __forceinline__ unsigned pk2(float a, float b) {
    return ((unsigned)bf16rn(b) << 16) | (unsigned)bf16rn(a);
}
__device__ __forceinline__ uint4 pack8(float4 f0, float4 f1) {
    uint4 u;
    u.x = pk2(f0.x, f0.y); u.y = pk2(f0.z, f0.w);
    u.z = pk2(f1.x, f1.y); u.w = pk2(f1.z, f1.w);
    return u;
}
__device__ __forceinline__ float bf2f(unsigned short u) {
    return __uint_as_float((unsigned)u << 16);
}
// fast activations: v_rcp_f32 instead of precise divide (serial-chain critical)
__device__ __forceinline__ float sigmf(float x) {
    return __builtin_amdgcn_rcpf(1.f + __expf(-x));
}
__device__ __forceinline__ float tanhf_(float x) {
    return 1.f - 2.f * __builtin_amdgcn_rcpf(__expf(2.f * x) + 1.f);
}

// ---------------------------------------------------------------------------
// K1: c[b][o] = relu(xf @ wf^T + conv_b), stored bf16.  M=128, N=50400, K=1344.
// (unchanged from previous verified version)
// ---------------------------------------------------------------------------
__global__ __launch_bounds__(256, 2)
void k1_conv_gemm(const float* __restrict__ x, const float* __restrict__ w,
                  const float* __restrict__ bias, unsigned short* __restrict__ c) {
    __shared__ uint4 a_lds[8 * 129];  // A: 128 rows (b), pad->129
    __shared__ uint4 b_lds[8 * 113];  // B: 112 rows (o), pad->113
    const int tid  = threadIdx.x;
    const int n0   = blockIdx.x * 112;
    const int wave = tid >> 6, lane = tid & 63;
    const int quad = lane >> 4, m16 = lane & 15;

    f32x4 acc[2][7];
#pragma unroll
    for (int i = 0; i < 2; ++i)
#pragma unroll
        for (int j = 0; j < 7; ++j) acc[i][j] = (f32x4){0.f, 0.f, 0.f, 0.f};

    float4 pa[4][2];  // A prefetch regs
    float4 pb[4][2];  // B prefetch regs

    auto issue = [&](int kb) {
#pragma unroll
        for (int i = 0; i < 4; ++i) {
            int row = (tid >> 3) + 32 * i;
            const float* gp = x + row * 1344 + kb + (tid & 7) * 8;
            pa[i][0] = *reinterpret_cast<const float4*>(gp);
            pa[i][1] = *reinterpret_cast<const float4*>(gp + 4);
        }
#pragma unroll
        for (int i = 0; i < 4; ++i) {
            int idx = tid + 256 * i;
            if (idx < 896) {
                int row = idx >> 3;
                const float* gp = w + (size_t)(n0 + row) * 1344 + kb + (idx & 7) * 8;
                pb[i][0] = *reinterpret_cast<const float4*>(gp);
                pb[i][1] = *reinterpret_cast<const float4*>(gp + 4);
            }
        }
    };

    issue(0);
    for (int kb = 0; kb < 1344; kb += 64) {
#pragma unroll
        for (int i = 0; i < 4; ++i) {
            int idx = tid + 256 * i;
            int row = idx >> 3, ks = idx & 7;
            a_lds[ks * 129 + row] = pack8(pa[i][0], pa[i][1]);
        }
#pragma unroll
        for (int i = 0; i < 4; ++i) {
            int idx = tid + 256 * i;
            if (idx < 896) {
                int row = idx >> 3, ks = idx & 7;
                b_lds[ks * 113 + row] = pack8(pb[i][0], pb[i][1]);
            }
        }
        __syncthreads();
        if (kb + 64 < 1344) issue(kb + 64);
#pragma unroll
        for (int half = 0; half < 2; ++half) {
            const int kp = half * 4 + quad;
            short8 af[2], bfr[7];
#pragma unroll
            for (int rt = 0; rt < 2; ++rt)
                af[rt] = ((const short8*)a_lds)[kp * 129 + wave * 32 + rt * 16 + m16];
#pragma unroll
            for (int ct = 0; ct < 7; ++ct)
                bfr[ct] = ((const short8*)b_lds)[kp * 113 + ct * 16 + m16];
#pragma unroll
            for (int rt = 0; rt < 2; ++rt)
#pragma unroll
                for (int ct = 0; ct < 7; ++ct)
                    acc[rt][ct] = __builtin_amdgcn_mfma_f32_16x16x32_bf16(
                        af[rt], bfr[ct], acc[rt][ct], 0, 0, 0);
        }
        __syncthreads();
    }
#pragma unroll
    for (int ct = 0; ct < 7; ++ct) {
        int col = n0 + ct * 16 + m16;
        float bv = bias[col];
#pragma unroll
        for (int rt = 0; rt < 2; ++rt) {
#pragma unroll
            for (int r = 0; r < 4; ++r) {
                int grow = wave * 32 + rt * 16 + quad * 4 + r;
                float v = acc[rt][ct][r] + bv;
                v = fmaxf(v, 0.f);
                c[(size_t)grow * 50400 + col] = bf16rn(v);
            }
        }
    }
}

// ---------------------------------------------------------------------------
// K_FUSED: everything after K1, one block per batch element b (128 blocks).
//   Phase A (6 waves): rloc[hc][t] = sum_k c[b][...]
//   Phase B (6 waves): gi1[t][150], gi2[pt*24+sk][15] into LDS.
//   barrier; waves 1..5 RETURN.
//   Phase C (wave 0 only, NO barriers): GRU1 163 steps. Weights pinned in
//   VGPRs (asm keep-alive), packed f32x2 math, single LDS h buffer
//   (in-order per-wave DS ops => no sync needed).
//   Then GRU2 (lanes 0..23, 6 steps) and final linear+highway (lanes 0..7).
// ---------------------------------------------------------------------------
__global__ __launch_bounds__(384, 1)
void k_fused(const unsigned short* __restrict__ c,
             const float* __restrict__ g1_wih, const float* __restrict__ g1_whh,
             const float* __restrict__ g1_bih, const float* __restrict__ g1_bhh,
             const float* __restrict__ gs_wih, const float* __restrict__ gs_whh,
             const float* __restrict__ gs_bih, const float* __restrict__ gs_bhh,
             const float* __restrict__ l1_w, const float* __restrict__ l1_b,
             const float* __restrict__ x, const float* __restrict__ hw_w,
             const float* __restrict__ hw_b, float* __restrict__ out) {
    __shared__ float rloc[50 * 164];   // [hc][t] pad 163->164
    __shared__ float gi1l[163 * 150];  // [t][150]
    __shared__ float gi2l[144 * 15];   // [(pt*24+sk)][15]
    __shared__ float l1wl[8 * 170];
    __shared__ __align__(16) float hl[64];
    __shared__ float hsl[120];
    __shared__ float r1l[50];

    const int b    = blockIdx.x;
    const int tid  = threadIdx.x;
    const int wave = tid >> 6, lane = tid & 63;

    // ---- Phase A: diagonal-sum into rloc ----
    const unsigned short* cb = c + (size_t)b * 50400;
    for (int idx = tid; idx < 8150; idx += 384) {
        int hc = idx / 163, t = idx - hc * 163;
        int base = hc * 1008 + t;
        float s = 0.f;
#pragma unroll
        for (int k = 0; k < 6; ++k) s += bf2f(cb[base + 169 * k]);
        rloc[hc * 164 + t] = s;
    }
    for (int idx = tid; idx < 1360; idx += 384) l1wl[idx] = l1_w[idx];
    __syncthreads();

    // ---- Phase B: input projections gi1 / gi2 into LDS ----
    {
        const int tB   = (wave >> 1) * 64 + lane;   // 0..191
        const int half = wave & 1;
        if (tB < 163) {
            float xcol[50];
#pragma unroll
            for (int j = 0; j < 50; ++j) xcol[j] = rloc[j * 164 + tB];

            const int c0 = __builtin_amdgcn_readfirstlane(half * 75);
            const float* wbase = g1_wih + c0 * 50;
            float* gdst = &gi1l[tB * 150 + c0];
            for (int cc = 0; cc < 75; ++cc) {
                const float* wp = wbase + cc * 50;
                float acc = g1_bih[c0 + cc];
#pragma unroll
                for (int j = 0; j < 50; ++j) acc += xcol[j] * wp[j];
                gdst[cc] = acc;
            }
            if (tB >= 19) {
                const int r2 = tB - 19;  // == pt*24 + sk
                const int d0 = __builtin_amdgcn_readfirstlane(half * 8);
                const int ncol = half ? 7 : 8;
                float* g2 = &gi2l[r2 * 15];
                for (int cc = 0; cc < ncol; ++cc) {
                    const float* wp = gs_wih + (d0 + cc) * 50;
                    float acc = gs_bih[d0 + cc];
#pragma unroll
                    for (int j = 0; j < 50; ++j) acc += xcol[j] * wp[j];
                    g2[d0 + cc] = acc;
                }
            }
        }
    }
    __syncthreads();
    if (wave != 0) return;   // waves 1..5 done; no barriers below

    // ---- Phase C: GRU1, single wave, weights in VGPRs ----
    const int lc = (lane < 50) ? lane : 49;
    f32x2 wr2[25], wz2[25], wn2[25];
    {
        const float* wrp = g1_whh + lc * 50;          // rows 8B-aligned (200 B)
        const float* wzp = g1_whh + (50 + lc) * 50;
        const float* wnp = g1_whh + (100 + lc) * 50;
#pragma unroll
        for (int j = 0; j < 25; ++j) {
            wr2[j] = *reinterpret_cast<const f32x2*>(wrp + 2 * j);
            wz2[j] = *reinterpret_cast<const f32x2*>(wzp + 2 * j);
            wn2[j] = *reinterpret_cast<const f32x2*>(wnp + 2 * j);
        }
#pragma unroll
        for (int j = 0; j < 25; ++j) {  // pin into VGPRs (defeat remat/spill)
            asm volatile("" : "+v"(wr2[j]));
            asm volatile("" : "+v"(wz2[j]));
            asm volatile("" : "+v"(wn2[j]));
        }
    }
    const float bhr = g1_bhh[lc], bhz = g1_bhh[50 + lc], bhn = g1_bhh[100 + lc];
    hl[lane] = 0.f;
    float hcur = 0.f;
    const float* gp = gi1l;
    for (int t = 0; t < 163; ++t) {
        float gir = gp[lc], giz = gp[50 + lc], gin = gp[100 + lc];
        float4 h4[12];
#pragma unroll
        for (int j4 = 0; j4 < 12; ++j4)
            h4[j4] = *reinterpret_cast<const float4*>(&hl[4 * j4]);
        f32x2 ht; ht.x = hl[48]; ht.y = hl[49];
        f32x2 ar = {0.f, 0.f}, az = {0.f, 0.f}, an = {0.f, 0.f};
#pragma unroll
        for (int j4 = 0; j4 < 12; ++j4) {
            f32x2 h0; h0.x = h4[j4].x; h0.y = h4[j4].y;
            f32x2 h1; h1.x = h4[j4].z; h1.y = h4[j4].w;
            ar += wr2[2 * j4] * h0; ar += wr2[2 * j4 + 1] * h1;
            az += wz2[2 * j4] * h0; az += wz2[2 * j4 + 1] * h1;
            an += wn2[2 * j4] * h0; an += wn2[2 * j4 + 1] * h1;
        }
        ar += wr2[24] * ht; az += wz2[24] * ht; an += wn2[24] * ht;
        float rg = sigmf(gir + bhr + ar.x + ar.y);
        float zg = sigmf(giz + bhz + az.x + az.y);
        float ng = tanhf_(gin + rg * (bhn + an.x + an.y));
        hcur = (1.f - zg) * ng + zg * hcur;
        hl[lane] = hcur;   // in-order DS: next iter's reads see this
        gp += 150;
    }
    if (lane < 50) r1l[lane] = hcur;

    // ---- GRU2: lanes 0..23, one sequence each (sk = lane), 6 steps ----
    if (lane < 24) {
        float h2[5] = {0.f, 0.f, 0.f, 0.f, 0.f};
        for (int pt = 0; pt < 6; ++pt) {
            const float* g2 = &gi2l[(pt * 24 + lane) * 15];
            float gi[15];
#pragma unroll
            for (int i = 0; i < 15; ++i) gi[i] = g2[i];
            float gh[15];
#pragma unroll
            for (int i = 0; i < 15; ++i) {
                float s = gs_bhh[i];
#pragma unroll
                for (int j = 0; j < 5; ++j) s += gs_whh[i * 5 + j] * h2[j];
                gh[i] = s;
            }
#pragma unroll
            for (int u = 0; u < 5; ++u) {
                float rg = sigmf(gi[u] + gh[u]);
                float zg = sigmf(gi[5 + u] + gh[5 + u]);
                float ng = tanhf_(gi[10 + u] + rg * gh[10 + u]);
                h2[u] = (1.f - zg) * ng + zg * h2[u];
            }
        }
#pragma unroll
        for (int u = 0; u < 5; ++u) hsl[lane * 5 + u] = h2[u];
    }

    // ---- Phase D: final linear + highway + sigmoid, lanes 0..7 ----
    if (lane < 8) {
        const int m = lane;
        float acc = l1_b[m];
        const float* wrow = &l1wl[m * 170];
#pragma unroll
        for (int j = 0; j < 50; ++j) acc += r1l[j] * wrow[j];
#pragma unroll
        for (int j = 0; j < 120; ++j) acc += hsl[j] * wrow[50 + j];
        float z = hw_b[0];
        const float* xb = x + (size_t)b * 1344 + 144 * 8 + m;
#pragma unroll
        for (int wi = 0; wi < 24; ++wi) z += xb[wi * 8] * hw_w[wi];
        out[b * 8 + m] = __builtin_amdgcn_rcpf(1.f + __expf(-(acc + z)));
    }
}

// ---------------------------------------------------------------------------
extern "C" void kernel_launch(void* const* d_in, const int* in_sizes, int n_in,
                              void* d_out, int out_size, void* d_ws, size_t ws_size,
                              hipStream_t stream) {
    const float* x      = (const float*)d_in[0];
    const float* conv_w = (const float*)d_in[1];
    const float* conv_b = (const float*)d_in[2];
    const float* g1_wih = (const float*)d_in[3];
    const float* g1_whh = (const float*)d_in[4];
    const float* g1_bih = (const float*)d_in[5];
    const float* g1_bhh = (const float*)d_in[6];
    const float* gs_wih = (const float*)d_in[7];
    const float* gs_whh = (const float*)d_in[8];
    const float* gs_bih = (const float*)d_in[9];
    const float* gs_bhh = (const float*)d_in[10];
    const float* l1_w   = (const float*)d_in[11];
    const float* l1_b   = (const float*)d_in[12];
    const float* hw_w   = (const float*)d_in[13];
    const float* hw_b   = (const float*)d_in[14];
    float* out = (float*)d_out;

    unsigned short* c = (unsigned short*)d_ws;  // 12,902,400 B

    hipLaunchKernelGGL(k1_conv_gemm, dim3(450), dim3(256), 0, stream, x, conv_w, conv_b, c);
    hipLaunchKernelGGL(k_fused,      dim3(128), dim3(384), 0, stream,
                       c, g1_wih, g1_whh, g1_bih, g1_bhh,
                       gs_wih, gs_whh, gs_bih, gs_bhh,
                       l1_w, l1_b, x, hw_w, hw_b, out);
}